// Round 1
// baseline (408.187 us; speedup 1.0000x reference)
//
#include <hip/hip_runtime.h>
#include <stdint.h>

#define OUT_DIM 8192
#define IN_DIM  8192
#define GS      128
#define MROWS   32
#define NSPLIT  8          // split-K chunks of 1024
#define PART_ELEMS (MROWS * OUT_DIM)

typedef __attribute__((ext_vector_type(8))) short bf16x8;   // MFMA A/B frag (4 VGPR)
typedef __attribute__((ext_vector_type(4))) float f32x4;    // MFMA C/D frag
typedef __attribute__((ext_vector_type(8))) unsigned short u16x8;
typedef __attribute__((ext_vector_type(2))) unsigned short u16x2;
typedef __attribute__((ext_vector_type(4))) unsigned int   u32x4;

__device__ __forceinline__ unsigned short f2bf_rne(float f) {
    uint32_t v = __builtin_bit_cast(uint32_t, f);
    v += 0x7FFFu + ((v >> 16) & 1u);
    return (unsigned short)(v >> 16);
}

// x (32x8192 fp32) -> bf16 workspace. 262144 elems, 8/thread, 128 blocks.
__global__ __launch_bounds__(256) void prep_xbf(const float* __restrict__ x,
                                                unsigned short* __restrict__ xbf) {
    int i = (blockIdx.x * 256 + threadIdx.x) * 8;
    float4 a = *(const float4*)(x + i);
    float4 b = *(const float4*)(x + i + 4);
    float f[8] = {a.x, a.y, a.z, a.w, b.x, b.y, b.z, b.w};
    u16x8 u;
#pragma unroll
    for (int j = 0; j < 8; ++j) u[j] = f2bf_rne(f[j]);
    *(u16x8*)(xbf + i) = u;
}

// Packed conversion: two ternary int32 -> two bf16 weights in one dword.
// t in {-1,0,1}. Low16(t): -1 -> 0xFFFF (sign bit set), 1 -> 0x0001, 0 -> 0.
//   v   = p32 | (t16 & 0x80008000)   per-half: scale bits with t's sign
//   |t| = t16 & 0x00010001           per-half: 0 or 1
//   r   = v * |t|  (v_pk_mul_lo_u16) per-half: 0 or signed scale bf16 bits
// = 5 VALU per pair (vs ~9 for and/or/cmp/cndmask/pack), output pre-packed.
__device__ __forceinline__ unsigned int cvt2(int t0, int t1, unsigned int p32) {
    unsigned int t16 = __builtin_amdgcn_perm((unsigned int)t1, (unsigned int)t0,
                                             0x05040100u);  // lo=t0.l16, hi=t1.l16
    unsigned int v   = p32 | (t16 & 0x80008000u);
    u16x2 r = __builtin_bit_cast(u16x2, v) *
              __builtin_bit_cast(u16x2, t16 & 0x00010001u);
    return __builtin_bit_cast(unsigned int, r);
}

__device__ __forceinline__ bf16x8 conv8(const int4 wa, const int4 wb, unsigned int p32) {
    u32x4 d;
    d[0] = cvt2(wa.x, wa.y, p32);
    d[1] = cvt2(wa.z, wa.w, p32);
    d[2] = cvt2(wb.x, wb.y, p32);
    d[3] = cvt2(wb.z, wb.w, p32);
    return __builtin_bit_cast(bf16x8, d);
}

// part[kc][t][o] = sum_{k in chunk kc} x[t][k] * ternary[o][k] * scale[o*64 + k/128]
// Wave: 16 o-cols x 32 t-rows (two 16x16x32 bf16 MFMA accs), K-chunk 1024.
// K=64 per step, 16 steps, named A/B register double-buffer: next step's 8 loads
// (4x int4 weights HBM + 4x bf16x8 x L2) are in flight while converting/MFMAing
// the current one -> per-wave outstanding bytes never drain to zero.
// (256,4): cap VGPR at 128 -> 4 blocks/CU, 1024-block grid fully resident, 1 round.
__global__ __launch_bounds__(256, 4) void ternary_gemm(
    const int* __restrict__ tern, const float* __restrict__ scales,
    const unsigned short* __restrict__ xbf, float* __restrict__ part) {
    const int wave  = blockIdx.x * 4 + (threadIdx.x >> 6);
    const int lane  = threadIdx.x & 63;
    const int kc    = wave >> 9;     // 0..7   split-K chunk
    const int ntile = wave & 511;    // 0..511 o-tile
    const int n     = lane & 15;
    const int quad  = lane >> 4;
    const int o     = (ntile << 4) + n;
    const int kbase = (kc << 10) + (quad << 3);   // fold lane's quad offset in

    const int* __restrict__ wrow            = tern + (size_t)o * IN_DIM + kbase;
    const unsigned short* __restrict__ xr0  = xbf + n * IN_DIM + kbase;        // x row n
    const unsigned short* __restrict__ xr1  = xbf + (16 + n) * IN_DIM + kbase; // x row 16+n
    const float* __restrict__ sp            = scales + o * (IN_DIM / GS) + (kc << 3);

    f32x4 acc0 = {0.f, 0.f, 0.f, 0.f};
    f32x4 acc1 = {0.f, 0.f, 0.f, 0.f};

    int4   wa0, wa1, wa2, wa3, wb0, wb1, wb2, wb3;
    bf16x8 xa0, xa1, xa2, xa3, xb0, xb1, xb2, xb3;

#define LOADA(IT) do { const int kk = (IT) << 6;                              \
        wa0 = *(const int4*)(wrow + kk);       wa1 = *(const int4*)(wrow + kk + 4);  \
        wa2 = *(const int4*)(wrow + kk + 32);  wa3 = *(const int4*)(wrow + kk + 36); \
        xa0 = *(const bf16x8*)(xr0 + kk);      xa1 = *(const bf16x8*)(xr0 + kk + 32);\
        xa2 = *(const bf16x8*)(xr1 + kk);      xa3 = *(const bf16x8*)(xr1 + kk + 32);\
    } while (0)
#define LOADB(IT) do { const int kk = (IT) << 6;                              \
        wb0 = *(const int4*)(wrow + kk);       wb1 = *(const int4*)(wrow + kk + 4);  \
        wb2 = *(const int4*)(wrow + kk + 32);  wb3 = *(const int4*)(wrow + kk + 36); \
        xb0 = *(const bf16x8*)(xr0 + kk);      xb1 = *(const bf16x8*)(xr0 + kk + 32);\
        xb2 = *(const bf16x8*)(xr1 + kk);      xb3 = *(const bf16x8*)(xr1 + kk + 32);\
    } while (0)
#define CONSA(P) do {                                                         \
        bf16x8 f0 = conv8(wa0, wa1, (P));  bf16x8 f1 = conv8(wa2, wa3, (P));  \
        acc0 = __builtin_amdgcn_mfma_f32_16x16x32_bf16(xa0, f0, acc0, 0, 0, 0);\
        acc1 = __builtin_amdgcn_mfma_f32_16x16x32_bf16(xa2, f0, acc1, 0, 0, 0);\
        acc0 = __builtin_amdgcn_mfma_f32_16x16x32_bf16(xa1, f1, acc0, 0, 0, 0);\
        acc1 = __builtin_amdgcn_mfma_f32_16x16x32_bf16(xa3, f1, acc1, 0, 0, 0);\
    } while (0)
#define CONSB(P) do {                                                         \
        bf16x8 f0 = conv8(wb0, wb1, (P));  bf16x8 f1 = conv8(wb2, wb3, (P));  \
        acc0 = __builtin_amdgcn_mfma_f32_16x16x32_bf16(xb0, f0, acc0, 0, 0, 0);\
        acc1 = __builtin_amdgcn_mfma_f32_16x16x32_bf16(xb2, f0, acc1, 0, 0, 0);\
        acc0 = __builtin_amdgcn_mfma_f32_16x16x32_bf16(xb1, f1, acc0, 0, 0, 0);\
        acc1 = __builtin_amdgcn_mfma_f32_16x16x32_bf16(xb3, f1, acc1, 0, 0, 0);\
    } while (0)

    LOADA(0);
    float s_cur = sp[0];

    // 8 pairs of K=64 steps; pair pr covers k-group pr (both steps share one scale).
#pragma unroll 1
    for (int pr = 0; pr < 8; ++pr) {
        const int it1 = (pr << 1) + 1;
        LOADB(it1);                                   // odd step's loads in flight
        float s_nxt = sp[(pr < 7) ? (pr + 1) : 7];    // next group's scale (L1-hot)
        const unsigned int ph  = f2bf_rne(s_cur);
        const unsigned int p32 = ph | (ph << 16);
        CONSA(p32);                                   // consume even step
        LOADA((pr < 7) ? (it1 + 1) : 15);             // next pair's even step
                                                      // (pr==7: L1-hit reload, dead)
        CONSB(p32);                                   // consume odd step
        s_cur = s_nxt;
    }
#undef LOADA
#undef LOADB
#undef CONSA
#undef CONSB

    // D layout: col = lane&15 (=o), row t = quad*4 + reg. Plain stores.
    float* __restrict__ prow = part + (size_t)kc * PART_ELEMS
                             + (size_t)(quad << 2) * OUT_DIM + o;
#pragma unroll
    for (int r = 0; r < 4; ++r) {
        prow[(size_t)r * OUT_DIM]        = acc0[r];
        prow[(size_t)(r + 16) * OUT_DIM] = acc1[r];
    }
}

// out = sum over 8 split-K partials. 256 blocks x 256 thr x float4.
__global__ __launch_bounds__(256) void reduce_parts(const float* __restrict__ part,
                                                    float* __restrict__ out) {
    const int i = (blockIdx.x * 256 + threadIdx.x) * 4;
    float4 s = *(const float4*)(part + i);
#pragma unroll
    for (int kc = 1; kc < NSPLIT; ++kc) {
        float4 v = *(const float4*)(part + (size_t)kc * PART_ELEMS + i);
        s.x += v.x; s.y += v.y; s.z += v.z; s.w += v.w;
    }
    *(float4*)(out + i) = s;
}

extern "C" void kernel_launch(void* const* d_in, const int* in_sizes, int n_in,
                              void* d_out, int out_size, void* d_ws, size_t ws_size,
                              hipStream_t stream) {
    const float* x      = (const float*)d_in[0];
    const int*   tern   = (const int*)d_in[1];
    const float* scales = (const float*)d_in[2];
    float* out = (float*)d_out;

    unsigned short* xbf = (unsigned short*)d_ws;                        // 512 KB
    float* part = (float*)((char*)d_ws + (512 << 10));                  // 8 MB

    prep_xbf<<<128, 256, 0, stream>>>(x, xbf);
    ternary_gemm<<<1024, 256, 0, stream>>>(tern, scales, xbf, part);
    reduce_parts<<<256, 256, 0, stream>>>(part, out);
}